// Round 2
// baseline (1539.872 us; speedup 1.0000x reference)
//
#include <hip/hip_runtime.h>
#include <hip/hip_bf16.h>
#include <math.h>

#define B_ 2
#define N_ 6
#define C_ 80
#define FH_ 16
#define FW_ 44
#define D_ 112
#define NX_ 128
#define NY_ 128

typedef __hip_bfloat16 bf16;

// dtype-flexible load: isbf selects bf16 vs f32 interpretation of the buffer
__device__ __forceinline__ float loadf(const void* p, int i, int isbf) {
  if (isbf) return __bfloat162float(((const bf16*)p)[i]);
  return ((const float*)p)[i];
}

// fp32 Gauss-Jordan 4x4 inverse with partial pivoting
__device__ void inv4(const float A[16], float out[16]) {
  float a[4][8];
  for (int i = 0; i < 4; i++) {
    for (int j = 0; j < 4; j++) {
      a[i][j] = A[i * 4 + j];
      a[i][j + 4] = (i == j) ? 1.f : 0.f;
    }
  }
  for (int c = 0; c < 4; c++) {
    int p = c;
    for (int r = c + 1; r < 4; r++)
      if (fabsf(a[r][c]) > fabsf(a[p][c])) p = r;
    if (p != c) {
      for (int j = 0; j < 8; j++) { float t = a[c][j]; a[c][j] = a[p][j]; a[p][j] = t; }
    }
    float piv = a[c][c];
    for (int j = 0; j < 8; j++) a[c][j] /= piv;
    for (int r = 0; r < 4; r++) {
      if (r == c) continue;
      float f = a[r][c];
      if (f != 0.f)
        for (int j = 0; j < 8; j++) a[r][j] -= f * a[c][j];
    }
  }
  for (int i = 0; i < 4; i++)
    for (int j = 0; j < 4; j++) out[i * 4 + j] = a[i][j + 4];
}

__device__ void mul4(const float A[16], const float Bm[16], float Cm[16]) {
  for (int i = 0; i < 4; i++)
    for (int j = 0; j < 4; j++) {
      float s = 0.f;
      for (int k = 0; k < 4; k++) s += A[i * 4 + k] * Bm[k * 4 + j];
      Cm[i * 4 + j] = s;
    }
}

// Detect dtypes + per-(b,n) fold: idaInv and M = bda @ s2e @ inv(intrin).
// flags[0]=tensors-are-bf16, flags[1]=mats-are-bf16.
__global__ void lss_prep(const void* __restrict__ logits,
                         const void* __restrict__ s2e, const void* __restrict__ intrin,
                         const void* __restrict__ ida, const void* __restrict__ bda,
                         float* __restrict__ mats, int* __restrict__ flags) {
  __shared__ int s_cnt;
  __shared__ int s_mats_bf, s_tens_bf;
  const int t = threadIdx.x;
  if (t == 0) s_cnt = 0;
  __syncthreads();
  // ---- tensor dtype probe: 256 even-index u16 samples of depth_logits ----
  {
    const unsigned short* u = (const unsigned short*)logits;
    unsigned short v = u[2 * t];  // in-bounds for both dtypes (min 1.89 MB buffer)
    int e = (v >> 7) & 0xFF;
    int plausible = (v == 0) || (e >= 110 && e <= 136);  // |x| in ~[1e-5, 1e3]
    if (plausible) atomicAdd(&s_cnt, 1);
  }
  __syncthreads();
  if (t == 0) {
    s_tens_bf = (s_cnt > 170) ? 1 : 0;  // bf16 ~256/256 plausible, f32 ~27/256
    // ---- matrix dtype probe: intrin[0][0]=560 as f32, denormal junk if bf16 ----
    float v = ((const float*)intrin)[0];
    s_mats_bf = (v > 100.f && v < 1.0e6f) ? 0 : 1;
    flags[0] = s_tens_bf;
    flags[1] = s_mats_bf;
  }
  __syncthreads();
  const int mbf = s_mats_bf;

  if (t < B_ * N_) {
    int b = t / N_;
    float S[16], I[16], A[16], Bd[16], Iinv[16], Ainv[16], Cm[16], M[16];
    for (int i = 0; i < 16; i++) {
      S[i]  = loadf(s2e,    t * 16 + i, mbf);
      I[i]  = loadf(intrin, t * 16 + i, mbf);
      A[i]  = loadf(ida,    t * 16 + i, mbf);
      Bd[i] = loadf(bda,    b * 16 + i, mbf);
    }
    inv4(I, Iinv);
    inv4(A, Ainv);
    mul4(S, Iinv, Cm);   // combine = s2e @ inv(intrin)
    mul4(Bd, Cm, M);     // fold bda
    for (int i = 0; i < 16; i++) {
      mats[t * 32 + i] = Ainv[i];
      mats[t * 32 + 16 + i] = M[i];
    }
  }
}

// One block per pixel column (b,n,h,w). 128 threads.
__global__ __launch_bounds__(128) void lss_main(
    const void* __restrict__ ctx, const void* __restrict__ logits,
    const float* __restrict__ mats, const int* __restrict__ flags,
    float* __restrict__ bev) {
  const int tid = threadIdx.x;
  const int col = blockIdx.x;
  const int w = col % FW_;
  const int h = (col / FW_) % FH_;
  const int bn = col / (FW_ * FH_);
  const int b = bn / N_;
  const int tbf = flags[0];

  __shared__ float s_w[D_];
  __shared__ int s_cell[D_];
  __shared__ float s_red[128];
  __shared__ float s_gw[D_];
  __shared__ int s_gcell[D_];
  __shared__ int s_gcnt;

  // ---- softmax over D ----
  float l = -1e30f;
  if (tid < D_) l = loadf(logits, ((bn * D_ + tid) * FH_ + h) * FW_ + w, tbf);
  s_red[tid] = l;
  __syncthreads();
  for (int s = 64; s > 0; s >>= 1) {
    if (tid < s) s_red[tid] = fmaxf(s_red[tid], s_red[tid + s]);
    __syncthreads();
  }
  float m = s_red[0];
  __syncthreads();
  float e = (tid < D_) ? expf(l - m) : 0.f;
  s_red[tid] = e;
  __syncthreads();
  for (int s = 64; s > 0; s >>= 1) {
    if (tid < s) s_red[tid] += s_red[tid + s];
    __syncthreads();
  }
  float inv_sum = 1.0f / s_red[0];

  if (tid == 0) s_gcnt = 0;

  // ---- geometry + voxel index per depth bin ----
  if (tid < D_) {
    const float* Ai = mats + bn * 32;
    const float* M = mats + bn * 32 + 16;
    float u = (float)w * (703.0f / 43.0f);
    float v = (float)h * 17.0f;
    float dep = 2.25f + 0.5f * (float)tid;
    float p0 = ((Ai[0] * u + Ai[1] * v) + Ai[2] * dep) + Ai[3];
    float p1 = ((Ai[4] * u + Ai[5] * v) + Ai[6] * dep) + Ai[7];
    float p2 = ((Ai[8] * u + Ai[9] * v) + Ai[10] * dep) + Ai[11];
    float p3 = ((Ai[12] * u + Ai[13] * v) + Ai[14] * dep) + Ai[15];
    float q0 = p0 * p2, q1 = p1 * p2;
    float gx = ((M[0] * q0 + M[1] * q1) + M[2] * p2) + M[3] * p3;
    float gy = ((M[4] * q0 + M[5] * q1) + M[6] * p2) + M[7] * p3;
    float gz = ((M[8] * q0 + M[9] * q1) + M[10] * p2) + M[11] * p3;
    const float OFFX = -51.2f;  // (vcoord - vsize/2) in fp32
    const float OFFZ = -5.0f;
    int ix = (int)floorf((gx - OFFX) / 0.8f);
    int iy = (int)floorf((gy - OFFX) / 0.8f);
    int iz = (int)floorf((gz - OFFZ) / 8.0f);
    bool valid = (ix >= 0) && (ix < NX_) && (iy >= 0) && (iy < NY_) && (iz == 0);
    s_w[tid] = e;
    s_cell[tid] = valid ? (iy * NX_ + ix) : -1;
  }
  __syncthreads();

  // ---- run-length group consecutive bins with same voxel ----
  if (tid < D_) {
    int vcell = s_cell[tid];
    if (vcell >= 0 && (tid == 0 || s_cell[tid - 1] != vcell)) {
      float acc = s_w[tid];
      for (int j = tid + 1; j < D_ && s_cell[j] == vcell; ++j) acc += s_w[j];
      int g = atomicAdd(&s_gcnt, 1);
      s_gcell[g] = vcell;
      s_gw[g] = acc * inv_sum;
    }
  }
  __syncthreads();

  // ---- scatter: thread c owns channel c ----
  int G = s_gcnt;
  if (tid < C_) {
    float cv = loadf(ctx, ((bn * C_ + tid) * FH_ + h) * FW_ + w, tbf);
    float* outb = bev + ((size_t)(b * C_ + tid)) * (NY_ * NX_);
    for (int g = 0; g < G; ++g) atomicAdd(&outb[s_gcell[g]], s_gw[g] * cv);
  }
}

__global__ void lss_convert(const float* __restrict__ bev, void* __restrict__ out,
                            const int* __restrict__ flags, int n) {
  int i = blockIdx.x * blockDim.x + threadIdx.x;
  if (i < n) {
    if (flags[0]) ((bf16*)out)[i] = __float2bfloat16(bev[i]);
    else ((float*)out)[i] = bev[i];
  }
}

extern "C" void kernel_launch(void* const* d_in, const int* in_sizes, int n_in,
                              void* d_out, int out_size, void* d_ws, size_t ws_size,
                              hipStream_t stream) {
  const void* ctx = d_in[0];
  const void* logits = d_in[1];
  const void* s2e = d_in[2];
  const void* intrin = d_in[3];
  const void* ida = d_in[4];
  const void* bda = d_in[5];

  float* wsf = (float*)d_ws;
  int* flags = (int*)d_ws;          // 2 ints
  float* mats = wsf + 16;           // 384 floats
  float* bev = wsf + 1024;          // B*C*NY*NX fp32 accumulator (10.5 MB)
  const int nbev = B_ * C_ * NY_ * NX_;

  hipMemsetAsync(bev, 0, (size_t)nbev * sizeof(float), stream);
  lss_prep<<<1, 256, 0, stream>>>(logits, s2e, intrin, ida, bda, mats, flags);
  lss_main<<<B_ * N_ * FH_ * FW_, 128, 0, stream>>>(ctx, logits, mats, flags, bev);
  lss_convert<<<(nbev + 255) / 256, 256, 0, stream>>>(bev, d_out, flags, nbev);
}

// Round 3
// 230.508 us; speedup vs baseline: 6.6804x; 6.6804x over previous
//
#include <hip/hip_runtime.h>
#include <hip/hip_bf16.h>
#include <math.h>

#define B_ 2
#define N_ 6
#define C_ 80
#define FH_ 16
#define FW_ 44
#define D_ 112
#define NX_ 128
#define NY_ 128
#define NCOL (B_ * N_ * FH_ * FW_)  /* 8448 */
#define NCELL (B_ * NY_ * NX_)      /* 32768 */
#define MAXT (NCOL * D_)            /* 946176 tuple capacity */

typedef __hip_bfloat16 bf16;
typedef unsigned short u16;

__device__ __forceinline__ float loadf(const void* p, int i, int isbf) {
  if (isbf) return __bfloat162float(((const bf16*)p)[i]);
  return ((const float*)p)[i];
}

// ---------- 4x4 helpers (fp32 Gauss-Jordan with partial pivoting) ----------
__device__ void inv4(const float A[16], float out[16]) {
  float a[4][8];
  for (int i = 0; i < 4; i++)
    for (int j = 0; j < 4; j++) { a[i][j] = A[i * 4 + j]; a[i][j + 4] = (i == j) ? 1.f : 0.f; }
  for (int c = 0; c < 4; c++) {
    int p = c;
    for (int r = c + 1; r < 4; r++) if (fabsf(a[r][c]) > fabsf(a[p][c])) p = r;
    if (p != c) for (int j = 0; j < 8; j++) { float t = a[c][j]; a[c][j] = a[p][j]; a[p][j] = t; }
    float piv = a[c][c];
    for (int j = 0; j < 8; j++) a[c][j] /= piv;
    for (int r = 0; r < 4; r++) {
      if (r == c) continue;
      float f = a[r][c];
      if (f != 0.f) for (int j = 0; j < 8; j++) a[r][j] -= f * a[c][j];
    }
  }
  for (int i = 0; i < 4; i++)
    for (int j = 0; j < 4; j++) out[i * 4 + j] = a[i][j + 4];
}

__device__ void mul4(const float A[16], const float Bm[16], float Cm[16]) {
  for (int i = 0; i < 4; i++)
    for (int j = 0; j < 4; j++) {
      float s = 0.f;
      for (int k = 0; k < 4; k++) s += A[i * 4 + k] * Bm[k * 4 + j];
      Cm[i * 4 + j] = s;
    }
}

// ---------- prep: dtype detect + matrix fold ----------
__global__ void lss_prep(const void* __restrict__ logits,
                         const void* __restrict__ s2e, const void* __restrict__ intrin,
                         const void* __restrict__ ida, const void* __restrict__ bda,
                         float* __restrict__ mats, int* __restrict__ flags) {
  __shared__ int s_cnt;
  __shared__ int s_mats_bf;
  const int t = threadIdx.x;
  if (t == 0) s_cnt = 0;
  __syncthreads();
  {
    const unsigned short* u = (const unsigned short*)logits;
    unsigned short v = u[2 * t];
    int e = (v >> 7) & 0xFF;
    if (v == 0 || (e >= 110 && e <= 136)) atomicAdd(&s_cnt, 1);
  }
  __syncthreads();
  if (t == 0) {
    flags[0] = (s_cnt > 170) ? 1 : 0;  // tensors bf16?
    float v = ((const float*)intrin)[0];
    s_mats_bf = (v > 100.f && v < 1.0e6f) ? 0 : 1;
    flags[1] = s_mats_bf;
  }
  __syncthreads();
  const int mbf = s_mats_bf;
  if (t < B_ * N_) {
    int b = t / N_;
    float S[16], I[16], A[16], Bd[16], Iinv[16], Ainv[16], Cm[16], M[16];
    for (int i = 0; i < 16; i++) {
      S[i]  = loadf(s2e,    t * 16 + i, mbf);
      I[i]  = loadf(intrin, t * 16 + i, mbf);
      A[i]  = loadf(ida,    t * 16 + i, mbf);
      Bd[i] = loadf(bda,    b * 16 + i, mbf);
    }
    inv4(I, Iinv);
    inv4(A, Ainv);
    mul4(S, Iinv, Cm);
    mul4(Bd, Cm, M);
    for (int i = 0; i < 16; i++) { mats[t * 32 + i] = Ainv[i]; mats[t * 32 + 16 + i] = M[i]; }
  }
}

// ---------- transpose ctx -> [col][c] fp32 (2.7 MB, L2-resident for gather) ----------
__global__ void lss_transpose(const void* __restrict__ ctx, const int* __restrict__ flags,
                              float* __restrict__ ctx_t) {
  int i = blockIdx.x * blockDim.x + threadIdx.x;
  if (i >= NCOL * C_) return;
  int col = i / C_, c = i - col * C_;
  int bn = col / (FH_ * FW_), r = col - bn * (FH_ * FW_);
  int h = r / FW_, w = r - h * FW_;
  ctx_t[i] = loadf(ctx, ((bn * C_ + c) * FH_ + h) * FW_ + w, flags[0]);
}

// ---------- shared geometry: voxel cell for (col, depth bin) ----------
__device__ __forceinline__ int geom_cell(const float* __restrict__ mats,
                                         int bn, int h, int w, int d) {
  const float* Ai = mats + bn * 32;
  const float* M = mats + bn * 32 + 16;
  float u = (float)w * (703.0f / 43.0f);
  float v = (float)h * 17.0f;
  float dep = 2.25f + 0.5f * (float)d;
  float p0 = ((Ai[0] * u + Ai[1] * v) + Ai[2] * dep) + Ai[3];
  float p1 = ((Ai[4] * u + Ai[5] * v) + Ai[6] * dep) + Ai[7];
  float p2 = ((Ai[8] * u + Ai[9] * v) + Ai[10] * dep) + Ai[11];
  float p3 = ((Ai[12] * u + Ai[13] * v) + Ai[14] * dep) + Ai[15];
  float q0 = p0 * p2, q1 = p1 * p2;
  float gx = ((M[0] * q0 + M[1] * q1) + M[2] * p2) + M[3] * p3;
  float gy = ((M[4] * q0 + M[5] * q1) + M[6] * p2) + M[7] * p3;
  float gz = ((M[8] * q0 + M[9] * q1) + M[10] * p2) + M[11] * p3;
  int ix = (int)floorf((gx + 51.2f) / 0.8f);
  int iy = (int)floorf((gy + 51.2f) / 0.8f);
  int iz = (int)floorf((gz + 5.0f) / 8.0f);
  bool valid = (ix >= 0) && (ix < NX_) && (iy >= 0) && (iy < NY_) && (iz == 0);
  int b = bn / N_;
  return valid ? (b * (NY_ * NX_) + iy * NX_ + ix) : -1;
}

// ---------- pass 1: count contributions per cell (geometry only, no softmax) ----------
__global__ __launch_bounds__(128) void lss_count(const float* __restrict__ mats,
                                                 int* __restrict__ counts) {
  const int tid = threadIdx.x;
  const int col = blockIdx.x;
  const int w = col % FW_;
  const int h = (col / FW_) % FH_;
  const int bn = col / (FW_ * FH_);
  __shared__ int s_cell[D_];
  if (tid < D_) s_cell[tid] = geom_cell(mats, bn, h, w, tid);
  __syncthreads();
  if (tid < D_) {
    int vcell = s_cell[tid];
    if (vcell >= 0 && (tid == 0 || s_cell[tid - 1] != vcell)) atomicAdd(&counts[vcell], 1);
  }
}

// ---------- exclusive scan of 32768 counts (single block) ----------
__global__ __launch_bounds__(1024) void lss_scan(const int* __restrict__ counts,
                                                 int* __restrict__ offsets,
                                                 int* __restrict__ cursors) {
  __shared__ int s[1024];
  const int t = threadIdx.x;
  const int base = t * 32;
  int local[32];
  int sum = 0;
  for (int j = 0; j < 32; j++) { local[j] = counts[base + j]; sum += local[j]; }
  s[t] = sum;
  __syncthreads();
  for (int st = 1; st < 1024; st <<= 1) {
    int v = (t >= st) ? s[t - st] : 0;
    __syncthreads();
    s[t] += v;
    __syncthreads();
  }
  int run = s[t] - sum;  // exclusive prefix of this thread's chunk
  for (int j = 0; j < 32; j++) {
    offsets[base + j] = run;
    cursors[base + j] = run;
    run += local[j];
  }
}

// ---------- pass 2: softmax + geometry, append (colid, weight) tuples ----------
__global__ __launch_bounds__(128) void lss_fill(
    const void* __restrict__ logits, const float* __restrict__ mats,
    const int* __restrict__ flags, int* __restrict__ cursors,
    u16* __restrict__ colids, float* __restrict__ wts) {
  const int tid = threadIdx.x;
  const int col = blockIdx.x;
  const int w = col % FW_;
  const int h = (col / FW_) % FH_;
  const int bn = col / (FW_ * FH_);
  const int tbf = flags[0];

  __shared__ float s_w[D_];
  __shared__ int s_cell[D_];
  __shared__ float s_red[128];

  float l = -1e30f;
  if (tid < D_) l = loadf(logits, ((bn * D_ + tid) * FH_ + h) * FW_ + w, tbf);
  s_red[tid] = l;
  __syncthreads();
  for (int s = 64; s > 0; s >>= 1) {
    if (tid < s) s_red[tid] = fmaxf(s_red[tid], s_red[tid + s]);
    __syncthreads();
  }
  float m = s_red[0];
  __syncthreads();
  float e = (tid < D_) ? expf(l - m) : 0.f;
  s_red[tid] = e;
  __syncthreads();
  for (int s = 64; s > 0; s >>= 1) {
    if (tid < s) s_red[tid] += s_red[tid + s];
    __syncthreads();
  }
  float inv_sum = 1.0f / s_red[0];

  if (tid < D_) {
    s_w[tid] = e;
    s_cell[tid] = geom_cell(mats, bn, h, w, tid);
  }
  __syncthreads();

  if (tid < D_) {
    int vcell = s_cell[tid];
    if (vcell >= 0 && (tid == 0 || s_cell[tid - 1] != vcell)) {
      float acc = s_w[tid];
      for (int j = tid + 1; j < D_ && s_cell[j] == vcell; ++j) acc += s_w[j];
      int pos = atomicAdd(&cursors[vcell], 1);
      colids[pos] = (u16)col;
      wts[pos] = acc * inv_sum;
    }
  }
}

// ---------- gather: one block per BEV cell, no atomics, single write ----------
__global__ __launch_bounds__(64) void lss_gather(
    const float* __restrict__ ctx_t, const int* __restrict__ counts,
    const int* __restrict__ offsets, const u16* __restrict__ colids,
    const float* __restrict__ wts, const int* __restrict__ flags,
    void* __restrict__ out) {
  __shared__ int s_col[64];
  __shared__ float s_wt[64];
  const int cell = blockIdx.x;
  const int tid = threadIdx.x;
  const int n = counts[cell];
  const int off = offsets[cell];
  float acc0 = 0.f, acc1 = 0.f;
  for (int base = 0; base < n; base += 64) {
    int k = min(64, n - base);
    if (tid < k) { s_col[tid] = colids[off + base + tid]; s_wt[tid] = wts[off + base + tid]; }
    __syncthreads();
    for (int j = 0; j < k; j++) {
      const float* cp = ctx_t + s_col[j] * C_;
      float wj = s_wt[j];
      acc0 += wj * cp[tid];
      if (tid < 16) acc1 += wj * cp[tid + 64];
    }
    __syncthreads();
  }
  const int b = cell >> 14;
  const int yx = cell & 16383;
  if (flags[0]) {
    bf16* o = (bf16*)out;
    o[(b * C_ + tid) * (NY_ * NX_) + yx] = __float2bfloat16(acc0);
    if (tid < 16) o[(b * C_ + tid + 64) * (NY_ * NX_) + yx] = __float2bfloat16(acc1);
  } else {
    float* o = (float*)out;
    o[(b * C_ + tid) * (NY_ * NX_) + yx] = acc0;
    if (tid < 16) o[(b * C_ + tid + 64) * (NY_ * NX_) + yx] = acc1;
  }
}

extern "C" void kernel_launch(void* const* d_in, const int* in_sizes, int n_in,
                              void* d_out, int out_size, void* d_ws, size_t ws_size,
                              hipStream_t stream) {
  const void* ctx = d_in[0];
  const void* logits = d_in[1];
  const void* s2e = d_in[2];
  const void* intrin = d_in[3];
  const void* ida = d_in[4];
  const void* bda = d_in[5];

  // ws layout (float units): flags[16] | mats[384] | counts[32768] |
  //   offsets[32768] | cursors[32768] | ctx_t[675840] | colids(u16 MAXT) | wts[MAXT]
  float* wsf = (float*)d_ws;
  int* flags   = (int*)wsf;
  float* mats  = wsf + 16;
  int* counts  = (int*)(wsf + 512);
  int* offsets = (int*)(wsf + 512 + NCELL);
  int* cursors = (int*)(wsf + 512 + 2 * NCELL);
  float* ctx_t = wsf + 512 + 3 * NCELL;                 // 675840 floats
  u16* colids  = (u16*)(ctx_t + NCOL * C_);             // MAXT u16 = 473088 floats
  float* wts   = (float*)((float*)colids + MAXT / 2);   // MAXT floats

  hipMemsetAsync(counts, 0, NCELL * sizeof(int), stream);
  lss_prep<<<1, 256, 0, stream>>>(logits, s2e, intrin, ida, bda, mats, flags);
  lss_transpose<<<(NCOL * C_ + 255) / 256, 256, 0, stream>>>(ctx, flags, ctx_t);
  lss_count<<<NCOL, 128, 0, stream>>>(mats, counts);
  lss_scan<<<1, 1024, 0, stream>>>(counts, offsets, cursors);
  lss_fill<<<NCOL, 128, 0, stream>>>(logits, mats, flags, cursors, colids, wts);
  lss_gather<<<NCELL, 64, 0, stream>>>(ctx_t, counts, offsets, colids, wts, flags, d_out);
}

// Round 4
// 230.412 us; speedup vs baseline: 6.6831x; 1.0004x over previous
//
#include <hip/hip_runtime.h>
#include <hip/hip_bf16.h>
#include <math.h>

#define B_ 2
#define N_ 6
#define C_ 80
#define FH_ 16
#define FW_ 44
#define D_ 112
#define NX_ 128
#define NY_ 128
#define NCOL (B_ * N_ * FH_ * FW_)  /* 8448 */
#define NCELL (B_ * NY_ * NX_)      /* 32768 */
#define MAXT (NCOL * D_)            /* 946176 tuple capacity */
#define GCELLS 64                   /* cells per gather block */

typedef __hip_bfloat16 bf16;
typedef unsigned short u16;

__device__ __forceinline__ float loadf(const void* p, int i, int isbf) {
  if (isbf) return __bfloat162float(((const bf16*)p)[i]);
  return ((const float*)p)[i];
}

// ---------- 4x4 helpers (fp32 Gauss-Jordan with partial pivoting) ----------
__device__ void inv4(const float A[16], float out[16]) {
  float a[4][8];
  for (int i = 0; i < 4; i++)
    for (int j = 0; j < 4; j++) { a[i][j] = A[i * 4 + j]; a[i][j + 4] = (i == j) ? 1.f : 0.f; }
  for (int c = 0; c < 4; c++) {
    int p = c;
    for (int r = c + 1; r < 4; r++) if (fabsf(a[r][c]) > fabsf(a[p][c])) p = r;
    if (p != c) for (int j = 0; j < 8; j++) { float t = a[c][j]; a[c][j] = a[p][j]; a[p][j] = t; }
    float piv = a[c][c];
    for (int j = 0; j < 8; j++) a[c][j] /= piv;
    for (int r = 0; r < 4; r++) {
      if (r == c) continue;
      float f = a[r][c];
      if (f != 0.f) for (int j = 0; j < 8; j++) a[r][j] -= f * a[c][j];
    }
  }
  for (int i = 0; i < 4; i++)
    for (int j = 0; j < 4; j++) out[i * 4 + j] = a[i][j + 4];
}

__device__ void mul4(const float A[16], const float Bm[16], float Cm[16]) {
  for (int i = 0; i < 4; i++)
    for (int j = 0; j < 4; j++) {
      float s = 0.f;
      for (int k = 0; k < 4; k++) s += A[i * 4 + k] * Bm[k * 4 + j];
      Cm[i * 4 + j] = s;
    }
}

// ---------- prep: dtype detect + matrix fold ----------
__global__ void lss_prep(const void* __restrict__ logits,
                         const void* __restrict__ s2e, const void* __restrict__ intrin,
                         const void* __restrict__ ida, const void* __restrict__ bda,
                         float* __restrict__ mats, int* __restrict__ flags) {
  __shared__ int s_cnt;
  __shared__ int s_mats_bf;
  const int t = threadIdx.x;
  if (t == 0) s_cnt = 0;
  __syncthreads();
  {
    const unsigned short* u = (const unsigned short*)logits;
    unsigned short v = u[2 * t];
    int e = (v >> 7) & 0xFF;
    if (v == 0 || (e >= 110 && e <= 136)) atomicAdd(&s_cnt, 1);
  }
  __syncthreads();
  if (t == 0) {
    flags[0] = (s_cnt > 170) ? 1 : 0;  // tensors bf16?
    float v = ((const float*)intrin)[0];
    s_mats_bf = (v > 100.f && v < 1.0e6f) ? 0 : 1;
    flags[1] = s_mats_bf;
  }
  __syncthreads();
  const int mbf = s_mats_bf;
  if (t < B_ * N_) {
    int b = t / N_;
    float S[16], I[16], A[16], Bd[16], Iinv[16], Ainv[16], Cm[16], M[16];
    for (int i = 0; i < 16; i++) {
      S[i]  = loadf(s2e,    t * 16 + i, mbf);
      I[i]  = loadf(intrin, t * 16 + i, mbf);
      A[i]  = loadf(ida,    t * 16 + i, mbf);
      Bd[i] = loadf(bda,    b * 16 + i, mbf);
    }
    inv4(I, Iinv);
    inv4(A, Ainv);
    mul4(S, Iinv, Cm);
    mul4(Bd, Cm, M);
    for (int i = 0; i < 16; i++) { mats[t * 32 + i] = Ainv[i]; mats[t * 32 + 16 + i] = M[i]; }
  }
}

// ---------- transpose ctx -> [col][c] fp32 (coalesced writes; reads L2-absorbed) ----------
__global__ void lss_transpose(const void* __restrict__ ctx, const int* __restrict__ flags,
                              float* __restrict__ ctx_t) {
  int i = blockIdx.x * blockDim.x + threadIdx.x;
  if (i >= NCOL * C_) return;
  int col = i / C_, c = i - col * C_;
  int bn = col / (FH_ * FW_), r = col - bn * (FH_ * FW_);
  int h = r / FW_, w = r - h * FW_;
  ctx_t[i] = loadf(ctx, ((bn * C_ + c) * FH_ + h) * FW_ + w, flags[0]);
}

// ---------- shared geometry: voxel cell for (col, depth bin) ----------
__device__ __forceinline__ int geom_cell(const float* __restrict__ mats,
                                         int bn, int h, int w, int d) {
  const float* Ai = mats + bn * 32;
  const float* M = mats + bn * 32 + 16;
  float u = (float)w * (703.0f / 43.0f);
  float v = (float)h * 17.0f;
  float dep = 2.25f + 0.5f * (float)d;
  float p0 = ((Ai[0] * u + Ai[1] * v) + Ai[2] * dep) + Ai[3];
  float p1 = ((Ai[4] * u + Ai[5] * v) + Ai[6] * dep) + Ai[7];
  float p2 = ((Ai[8] * u + Ai[9] * v) + Ai[10] * dep) + Ai[11];
  float p3 = ((Ai[12] * u + Ai[13] * v) + Ai[14] * dep) + Ai[15];
  float q0 = p0 * p2, q1 = p1 * p2;
  float gx = ((M[0] * q0 + M[1] * q1) + M[2] * p2) + M[3] * p3;
  float gy = ((M[4] * q0 + M[5] * q1) + M[6] * p2) + M[7] * p3;
  float gz = ((M[8] * q0 + M[9] * q1) + M[10] * p2) + M[11] * p3;
  int ix = (int)floorf((gx + 51.2f) / 0.8f);
  int iy = (int)floorf((gy + 51.2f) / 0.8f);
  int iz = (int)floorf((gz + 5.0f) / 8.0f);
  bool valid = (ix >= 0) && (ix < NX_) && (iy >= 0) && (iy < NY_) && (iz == 0);
  int b = bn / N_;
  return valid ? (b * (NY_ * NX_) + iy * NX_ + ix) : -1;
}

// ---------- pass 1: count contributions per cell (single wave, 2 bins/thread) ----------
__global__ __launch_bounds__(64) void lss_count(const float* __restrict__ mats,
                                                int* __restrict__ counts) {
  const int tid = threadIdx.x;
  const int col = blockIdx.x;
  const int w = col % FW_;
  const int h = (col / FW_) % FH_;
  const int bn = col / (FW_ * FH_);
  __shared__ int s_cell[D_];
  s_cell[tid] = geom_cell(mats, bn, h, w, tid);
  if (tid < D_ - 64) s_cell[tid + 64] = geom_cell(mats, bn, h, w, tid + 64);
  __syncthreads();
  for (int d = tid; d < D_; d += 64) {
    int vcell = s_cell[d];
    if (vcell >= 0 && (d == 0 || s_cell[d - 1] != vcell)) atomicAdd(&counts[vcell], 1);
  }
}

// ---------- exclusive scan of 32768 counts (single block) ----------
__global__ __launch_bounds__(1024) void lss_scan(const int* __restrict__ counts,
                                                 int* __restrict__ offsets,
                                                 int* __restrict__ cursors) {
  __shared__ int s[1024];
  const int t = threadIdx.x;
  const int base = t * 32;
  int local[32];
  int sum = 0;
  for (int j = 0; j < 32; j++) { local[j] = counts[base + j]; sum += local[j]; }
  s[t] = sum;
  __syncthreads();
  for (int st = 1; st < 1024; st <<= 1) {
    int v = (t >= st) ? s[t - st] : 0;
    __syncthreads();
    s[t] += v;
    __syncthreads();
  }
  int run = s[t] - sum;
  for (int j = 0; j < 32; j++) {
    offsets[base + j] = run;
    cursors[base + j] = run;
    run += local[j];
  }
}

// ---------- pass 2: wave softmax + geometry, append (colid, weight) tuples ----------
__global__ __launch_bounds__(64) void lss_fill(
    const void* __restrict__ logits, const float* __restrict__ mats,
    const int* __restrict__ flags, int* __restrict__ cursors,
    u16* __restrict__ colids, float* __restrict__ wts) {
  const int tid = threadIdx.x;
  const int col = blockIdx.x;
  const int w = col % FW_;
  const int h = (col / FW_) % FH_;
  const int bn = col / (FW_ * FH_);
  const int tbf = flags[0];

  __shared__ float s_w[D_];
  __shared__ int s_cell[D_];

  const int base = ((bn * D_) * FH_ + h) * FW_ + w;  // + d*FH_*FW_
  float l0 = loadf(logits, base + tid * (FH_ * FW_), tbf);
  float l1 = (tid < D_ - 64) ? loadf(logits, base + (tid + 64) * (FH_ * FW_), tbf) : -1e30f;
  float m = fmaxf(l0, l1);
  for (int s = 32; s > 0; s >>= 1) m = fmaxf(m, __shfl_xor(m, s));
  float e0 = expf(l0 - m);
  float e1 = (tid < D_ - 64) ? expf(l1 - m) : 0.f;
  float sum = e0 + e1;
  for (int s = 32; s > 0; s >>= 1) sum += __shfl_xor(sum, s);
  float inv_sum = 1.0f / sum;

  s_w[tid] = e0;
  s_cell[tid] = geom_cell(mats, bn, h, w, tid);
  if (tid < D_ - 64) {
    s_w[tid + 64] = e1;
    s_cell[tid + 64] = geom_cell(mats, bn, h, w, tid + 64);
  }
  __syncthreads();

  for (int d = tid; d < D_; d += 64) {
    int vcell = s_cell[d];
    if (vcell >= 0 && (d == 0 || s_cell[d - 1] != vcell)) {
      float acc = s_w[d];
      for (int j = d + 1; j < D_ && s_cell[j] == vcell; ++j) acc += s_w[j];
      int pos = atomicAdd(&cursors[vcell], 1);
      colids[pos] = (u16)col;
      wts[pos] = acc * inv_sum;
    }
  }
}

// ---------- gather v2: 256 threads / 64 consecutive cells, coalesced writes ----------
__global__ __launch_bounds__(256) void lss_gather(
    const float* __restrict__ ctx_t, const int* __restrict__ counts,
    const int* __restrict__ offsets, const u16* __restrict__ colids,
    const float* __restrict__ wts, const int* __restrict__ flags,
    void* __restrict__ out) {
  __shared__ float s_acc[GCELLS * 81];  // stride 81: conflict-free column reads
  const int tid = threadIdx.x;
  const int cell0 = blockIdx.x * GCELLS;
  const int cl = tid >> 2;      // local cell 0..63
  const int g = tid & 3;        // channel quarter: 20 channels
  const int cell = cell0 + cl;
  const int n = counts[cell];
  const int off = offsets[cell];

  float acc[20];
#pragma unroll
  for (int i = 0; i < 20; i++) acc[i] = 0.f;

  for (int j = 0; j < n; j++) {
    int colj = colids[off + j];
    float wj = wts[off + j];
    const float4* cp = (const float4*)(ctx_t + colj * C_ + g * 20);
#pragma unroll
    for (int q = 0; q < 5; q++) {
      float4 v = cp[q];
      acc[q * 4 + 0] += wj * v.x;
      acc[q * 4 + 1] += wj * v.y;
      acc[q * 4 + 2] += wj * v.z;
      acc[q * 4 + 3] += wj * v.w;
    }
  }
#pragma unroll
  for (int i = 0; i < 20; i++) s_acc[cl * 81 + g * 20 + i] = acc[i];
  __syncthreads();

  // coalesced write: wave r covers all 64 cells for channels c = r, r+4, ...
  const int r = tid >> 6;       // 0..3
  const int x = tid & 63;       // cell within block
  const int b = cell0 >> 14;    // cell0 / (NY*NX)
  const int yx0 = cell0 & 16383;
  if (flags[0]) {
    bf16* o = (bf16*)out;
    for (int c = r; c < C_; c += 4)
      o[(size_t)(b * C_ + c) * (NY_ * NX_) + yx0 + x] = __float2bfloat16(s_acc[x * 81 + c]);
  } else {
    float* o = (float*)out;
    for (int c = r; c < C_; c += 4)
      o[(size_t)(b * C_ + c) * (NY_ * NX_) + yx0 + x] = s_acc[x * 81 + c];
  }
}

extern "C" void kernel_launch(void* const* d_in, const int* in_sizes, int n_in,
                              void* d_out, int out_size, void* d_ws, size_t ws_size,
                              hipStream_t stream) {
  const void* ctx = d_in[0];
  const void* logits = d_in[1];
  const void* s2e = d_in[2];
  const void* intrin = d_in[3];
  const void* ida = d_in[4];
  const void* bda = d_in[5];

  // ws layout (float units): flags[16]+mats[...] (512) | counts | offsets | cursors |
  //   ctx_t[NCOL*C] | colids(u16,MAXT) | wts[MAXT]   — total ~8.8 MB
  float* wsf = (float*)d_ws;
  int* flags   = (int*)wsf;
  float* mats  = wsf + 16;
  int* counts  = (int*)(wsf + 512);
  int* offsets = (int*)(wsf + 512 + NCELL);
  int* cursors = (int*)(wsf + 512 + 2 * NCELL);
  float* ctx_t = wsf + 512 + 3 * NCELL;
  u16* colids  = (u16*)(ctx_t + NCOL * C_);
  float* wts   = (float*)((float*)colids + MAXT / 2);

  hipMemsetAsync(counts, 0, NCELL * sizeof(int), stream);
  lss_prep<<<1, 256, 0, stream>>>(logits, s2e, intrin, ida, bda, mats, flags);
  lss_transpose<<<(NCOL * C_ + 255) / 256, 256, 0, stream>>>(ctx, flags, ctx_t);
  lss_count<<<NCOL, 64, 0, stream>>>(mats, counts);
  lss_scan<<<1, 1024, 0, stream>>>(counts, offsets, cursors);
  lss_fill<<<NCOL, 64, 0, stream>>>(logits, mats, flags, cursors, colids, wts);
  lss_gather<<<NCELL / GCELLS, 256, 0, stream>>>(ctx_t, counts, offsets, colids, wts, flags, d_out);
}

// Round 5
// 193.865 us; speedup vs baseline: 7.9430x; 1.1885x over previous
//
#include <hip/hip_runtime.h>
#include <hip/hip_bf16.h>
#include <math.h>

#define B_ 2
#define N_ 6
#define C_ 80
#define FH_ 16
#define FW_ 44
#define D_ 112
#define NX_ 128
#define NY_ 128
#define NCOL (B_ * N_ * FH_ * FW_)  /* 8448 */
#define NCELL (B_ * NY_ * NX_)      /* 32768 */
#define MAXT (NCOL * D_)            /* 946176 tuple capacity */
#define GB_CELLS 16                 /* cells per gather block (1 wave each) */

typedef __hip_bfloat16 bf16;
typedef unsigned short u16;

__device__ __forceinline__ float loadf(const void* p, int i, int isbf) {
  if (isbf) return __bfloat162float(((const bf16*)p)[i]);
  return ((const float*)p)[i];
}

// ---------- adjugate 4x4 inverse: static indexing only (no scratch!) ----------
__device__ void inv4(const float m[16], float invOut[16]) {
  float inv[16];
  inv[0]  =  m[5]*m[10]*m[15] - m[5]*m[11]*m[14] - m[9]*m[6]*m[15] + m[9]*m[7]*m[14] + m[13]*m[6]*m[11] - m[13]*m[7]*m[10];
  inv[4]  = -m[4]*m[10]*m[15] + m[4]*m[11]*m[14] + m[8]*m[6]*m[15] - m[8]*m[7]*m[14] - m[12]*m[6]*m[11] + m[12]*m[7]*m[10];
  inv[8]  =  m[4]*m[9]*m[15]  - m[4]*m[11]*m[13] - m[8]*m[5]*m[15] + m[8]*m[7]*m[13] + m[12]*m[5]*m[11] - m[12]*m[7]*m[9];
  inv[12] = -m[4]*m[9]*m[14]  + m[4]*m[10]*m[13] + m[8]*m[5]*m[14] - m[8]*m[6]*m[13] - m[12]*m[5]*m[10] + m[12]*m[6]*m[9];
  inv[1]  = -m[1]*m[10]*m[15] + m[1]*m[11]*m[14] + m[9]*m[2]*m[15] - m[9]*m[3]*m[14] - m[13]*m[2]*m[11] + m[13]*m[3]*m[10];
  inv[5]  =  m[0]*m[10]*m[15] - m[0]*m[11]*m[14] - m[8]*m[2]*m[15] + m[8]*m[3]*m[14] + m[12]*m[2]*m[11] - m[12]*m[3]*m[10];
  inv[9]  = -m[0]*m[9]*m[15]  + m[0]*m[11]*m[13] + m[8]*m[1]*m[15] - m[8]*m[3]*m[13] - m[12]*m[1]*m[11] + m[12]*m[3]*m[9];
  inv[13] =  m[0]*m[9]*m[14]  - m[0]*m[10]*m[13] - m[8]*m[1]*m[14] + m[8]*m[2]*m[13] + m[12]*m[1]*m[10] - m[12]*m[2]*m[9];
  inv[2]  =  m[1]*m[6]*m[15]  - m[1]*m[7]*m[14]  - m[5]*m[2]*m[15] + m[5]*m[3]*m[14] + m[13]*m[2]*m[7]  - m[13]*m[3]*m[6];
  inv[6]  = -m[0]*m[6]*m[15]  + m[0]*m[7]*m[14]  + m[4]*m[2]*m[15] - m[4]*m[3]*m[14] - m[12]*m[2]*m[7]  + m[12]*m[3]*m[6];
  inv[10] =  m[0]*m[5]*m[15]  - m[0]*m[7]*m[13]  - m[4]*m[1]*m[15] + m[4]*m[3]*m[13] + m[12]*m[1]*m[7]  - m[12]*m[3]*m[5];
  inv[14] = -m[0]*m[5]*m[14]  + m[0]*m[6]*m[13]  + m[4]*m[1]*m[14] - m[4]*m[2]*m[13] - m[12]*m[1]*m[6]  + m[12]*m[2]*m[5];
  inv[3]  = -m[1]*m[6]*m[11]  + m[1]*m[7]*m[10]  + m[5]*m[2]*m[11] - m[5]*m[3]*m[10] - m[9]*m[2]*m[7]   + m[9]*m[3]*m[6];
  inv[7]  =  m[0]*m[6]*m[11]  - m[0]*m[7]*m[10]  - m[4]*m[2]*m[11] + m[4]*m[3]*m[10] + m[8]*m[2]*m[7]   - m[8]*m[3]*m[6];
  inv[11] = -m[0]*m[5]*m[11]  + m[0]*m[7]*m[9]   + m[4]*m[1]*m[11] - m[4]*m[3]*m[9]  - m[8]*m[1]*m[7]   + m[8]*m[3]*m[5];
  inv[15] =  m[0]*m[5]*m[10]  - m[0]*m[6]*m[9]   - m[4]*m[1]*m[10] + m[4]*m[2]*m[9]  + m[8]*m[1]*m[6]   - m[8]*m[2]*m[5];
  float det = m[0]*inv[0] + m[1]*inv[4] + m[2]*inv[8] + m[3]*inv[12];
  det = 1.0f / det;
  for (int i = 0; i < 16; i++) invOut[i] = inv[i] * det;
}

__device__ void mul4(const float A[16], const float Bm[16], float Cm[16]) {
  for (int i = 0; i < 4; i++)
    for (int j = 0; j < 4; j++) {
      float s = 0.f;
      for (int k = 0; k < 4; k++) s += A[i * 4 + k] * Bm[k * 4 + j];
      Cm[i * 4 + j] = s;
    }
}

// ---------- prep: dtype detect + matrix fold ----------
__global__ void lss_prep(const void* __restrict__ logits,
                         const void* __restrict__ s2e, const void* __restrict__ intrin,
                         const void* __restrict__ ida, const void* __restrict__ bda,
                         float* __restrict__ mats, int* __restrict__ flags) {
  __shared__ int s_cnt;
  __shared__ int s_mats_bf;
  const int t = threadIdx.x;
  if (t == 0) s_cnt = 0;
  __syncthreads();
  {
    const unsigned short* u = (const unsigned short*)logits;
    unsigned short v = u[2 * t];
    int e = (v >> 7) & 0xFF;
    if (v == 0 || (e >= 110 && e <= 136)) atomicAdd(&s_cnt, 1);
  }
  __syncthreads();
  if (t == 0) {
    flags[0] = (s_cnt > 170) ? 1 : 0;  // tensors bf16?
    float v = ((const float*)intrin)[0];
    s_mats_bf = (v > 100.f && v < 1.0e6f) ? 0 : 1;
    flags[1] = s_mats_bf;
  }
  __syncthreads();
  const int mbf = s_mats_bf;
  if (t < B_ * N_) {
    int b = t / N_;
    float S[16], I[16], A[16], Bd[16], Iinv[16], Ainv[16], Cm[16], M[16];
    for (int i = 0; i < 16; i++) {
      S[i]  = loadf(s2e,    t * 16 + i, mbf);
      I[i]  = loadf(intrin, t * 16 + i, mbf);
      A[i]  = loadf(ida,    t * 16 + i, mbf);
      Bd[i] = loadf(bda,    b * 16 + i, mbf);
    }
    inv4(I, Iinv);
    inv4(A, Ainv);
    mul4(S, Iinv, Cm);
    mul4(Bd, Cm, M);
    for (int i = 0; i < 16; i++) { mats[t * 32 + i] = Ainv[i]; mats[t * 32 + 16 + i] = M[i]; }
  }
}

// ---------- transpose ctx -> [col][c] fp32 ----------
__global__ void lss_transpose(const void* __restrict__ ctx, const int* __restrict__ flags,
                              float* __restrict__ ctx_t) {
  int i = blockIdx.x * blockDim.x + threadIdx.x;
  if (i >= NCOL * C_) return;
  int col = i / C_, c = i - col * C_;
  int bn = col / (FH_ * FW_), r = col - bn * (FH_ * FW_);
  int h = r / FW_, w = r - h * FW_;
  ctx_t[i] = loadf(ctx, ((bn * C_ + c) * FH_ + h) * FW_ + w, flags[0]);
}

// ---------- shared geometry: voxel cell for (col, depth bin) ----------
__device__ __forceinline__ int geom_cell(const float* __restrict__ mats,
                                         int bn, int h, int w, int d) {
  const float* Ai = mats + bn * 32;
  const float* M = mats + bn * 32 + 16;
  float u = (float)w * (703.0f / 43.0f);
  float v = (float)h * 17.0f;
  float dep = 2.25f + 0.5f * (float)d;
  float p0 = ((Ai[0] * u + Ai[1] * v) + Ai[2] * dep) + Ai[3];
  float p1 = ((Ai[4] * u + Ai[5] * v) + Ai[6] * dep) + Ai[7];
  float p2 = ((Ai[8] * u + Ai[9] * v) + Ai[10] * dep) + Ai[11];
  float p3 = ((Ai[12] * u + Ai[13] * v) + Ai[14] * dep) + Ai[15];
  float q0 = p0 * p2, q1 = p1 * p2;
  float gx = ((M[0] * q0 + M[1] * q1) + M[2] * p2) + M[3] * p3;
  float gy = ((M[4] * q0 + M[5] * q1) + M[6] * p2) + M[7] * p3;
  float gz = ((M[8] * q0 + M[9] * q1) + M[10] * p2) + M[11] * p3;
  int ix = (int)floorf((gx + 51.2f) / 0.8f);
  int iy = (int)floorf((gy + 51.2f) / 0.8f);
  int iz = (int)floorf((gz + 5.0f) / 8.0f);
  bool valid = (ix >= 0) && (ix < NX_) && (iy >= 0) && (iy < NY_) && (iz == 0);
  int b = bn / N_;
  return valid ? (b * (NY_ * NX_) + iy * NX_ + ix) : -1;
}

// ---------- pass 1: count contributions per cell ----------
__global__ __launch_bounds__(64) void lss_count(const float* __restrict__ mats,
                                                int* __restrict__ counts) {
  const int tid = threadIdx.x;
  const int col = blockIdx.x;
  const int w = col % FW_;
  const int h = (col / FW_) % FH_;
  const int bn = col / (FW_ * FH_);
  __shared__ int s_cell[D_];
  s_cell[tid] = geom_cell(mats, bn, h, w, tid);
  if (tid < D_ - 64) s_cell[tid + 64] = geom_cell(mats, bn, h, w, tid + 64);
  __syncthreads();
  for (int d = tid; d < D_; d += 64) {
    int vcell = s_cell[d];
    if (vcell >= 0 && (d == 0 || s_cell[d - 1] != vcell)) atomicAdd(&counts[vcell], 1);
  }
}

// ---------- exclusive scan of 32768 counts (single block) ----------
__global__ __launch_bounds__(1024) void lss_scan(const int* __restrict__ counts,
                                                 int* __restrict__ offsets,
                                                 int* __restrict__ cursors) {
  __shared__ int s[1024];
  const int t = threadIdx.x;
  const int base = t * 32;
  int local[32];
  int sum = 0;
  for (int j = 0; j < 32; j++) { local[j] = counts[base + j]; sum += local[j]; }
  s[t] = sum;
  __syncthreads();
  for (int st = 1; st < 1024; st <<= 1) {
    int v = (t >= st) ? s[t - st] : 0;
    __syncthreads();
    s[t] += v;
    __syncthreads();
  }
  int run = s[t] - sum;
  for (int j = 0; j < 32; j++) {
    offsets[base + j] = run;
    cursors[base + j] = run;
    run += local[j];
  }
}

// ---------- pass 2: wave softmax + geometry, append (colid, weight) tuples ----------
__global__ __launch_bounds__(64) void lss_fill(
    const void* __restrict__ logits, const float* __restrict__ mats,
    const int* __restrict__ flags, int* __restrict__ cursors,
    u16* __restrict__ colids, float* __restrict__ wts) {
  const int tid = threadIdx.x;
  const int col = blockIdx.x;
  const int w = col % FW_;
  const int h = (col / FW_) % FH_;
  const int bn = col / (FW_ * FH_);
  const int tbf = flags[0];

  __shared__ float s_w[D_];
  __shared__ int s_cell[D_];

  const int base = ((bn * D_) * FH_ + h) * FW_ + w;
  float l0 = loadf(logits, base + tid * (FH_ * FW_), tbf);
  float l1 = (tid < D_ - 64) ? loadf(logits, base + (tid + 64) * (FH_ * FW_), tbf) : -1e30f;
  float m = fmaxf(l0, l1);
  for (int s = 32; s > 0; s >>= 1) m = fmaxf(m, __shfl_xor(m, s));
  float e0 = expf(l0 - m);
  float e1 = (tid < D_ - 64) ? expf(l1 - m) : 0.f;
  float sum = e0 + e1;
  for (int s = 32; s > 0; s >>= 1) sum += __shfl_xor(sum, s);
  float inv_sum = 1.0f / sum;

  s_w[tid] = e0;
  s_cell[tid] = geom_cell(mats, bn, h, w, tid);
  if (tid < D_ - 64) {
    s_w[tid + 64] = e1;
    s_cell[tid + 64] = geom_cell(mats, bn, h, w, tid + 64);
  }
  __syncthreads();

  for (int d = tid; d < D_; d += 64) {
    int vcell = s_cell[d];
    if (vcell >= 0 && (d == 0 || s_cell[d - 1] != vcell)) {
      float acc = s_w[d];
      for (int j = d + 1; j < D_ && s_cell[j] == vcell; ++j) acc += s_w[j];
      int pos = atomicAdd(&cursors[vcell], 1);
      colids[pos] = (u16)col;
      wts[pos] = acc * inv_sum;
    }
  }
}

// ---------- gather v3: one wave per cell; 16 j-slices x 4 channel-quarters ----------
__global__ __launch_bounds__(1024) void lss_gather(
    const float* __restrict__ ctx_t, const int* __restrict__ counts,
    const int* __restrict__ offsets, const u16* __restrict__ colids,
    const float* __restrict__ wts, const int* __restrict__ flags,
    void* __restrict__ out) {
  __shared__ float s_out[GB_CELLS * 84];
  const int tid = threadIdx.x;
  const int wv = tid >> 6;          // local cell 0..15
  const int ln = tid & 63;
  const int sl = ln >> 2;           // j-slice 0..15 (lane bits 2..5)
  const int g = ln & 3;             // channel quarter
  const int cell = blockIdx.x * GB_CELLS + wv;
  const int n = counts[cell];
  const int off = offsets[cell];

  float acc[20];
#pragma unroll
  for (int i = 0; i < 20; i++) acc[i] = 0.f;

  for (int j = sl; j < n; j += 16) {
    int colj = colids[off + j];
    float wj = wts[off + j];
    const float4* cp = (const float4*)(ctx_t + colj * C_ + g * 20);
#pragma unroll
    for (int q = 0; q < 5; q++) {
      float4 v = cp[q];
      acc[q * 4 + 0] += wj * v.x;
      acc[q * 4 + 1] += wj * v.y;
      acc[q * 4 + 2] += wj * v.z;
      acc[q * 4 + 3] += wj * v.w;
    }
  }
  // reduce across slice lanes (bits 2..5)
#pragma unroll
  for (int msk = 4; msk <= 32; msk <<= 1) {
#pragma unroll
    for (int i = 0; i < 20; i++) acc[i] += __shfl_xor(acc[i], msk);
  }
  if (sl == 0) {
#pragma unroll
    for (int i = 0; i < 20; i++) s_out[wv * 84 + g * 20 + i] = acc[i];
  }
  __syncthreads();

  // write: x = cell-in-block (16 consecutive yx), c = channel
  const int x = tid & 15;
  const int c0 = tid >> 4;          // 0..63
  const int cell0 = blockIdx.x * GB_CELLS;
  const int b = cell0 >> 14;
  const int yx0 = cell0 & 16383;
  if (flags[0]) {
    bf16* o = (bf16*)out;
    o[(size_t)(b * C_ + c0) * (NY_ * NX_) + yx0 + x] = __float2bfloat16(s_out[x * 84 + c0]);
    if (c0 < 16)
      o[(size_t)(b * C_ + 64 + c0) * (NY_ * NX_) + yx0 + x] = __float2bfloat16(s_out[x * 84 + 64 + c0]);
  } else {
    float* o = (float*)out;
    o[(size_t)(b * C_ + c0) * (NY_ * NX_) + yx0 + x] = s_out[x * 84 + c0];
    if (c0 < 16)
      o[(size_t)(b * C_ + 64 + c0) * (NY_ * NX_) + yx0 + x] = s_out[x * 84 + 64 + c0];
  }
}

extern "C" void kernel_launch(void* const* d_in, const int* in_sizes, int n_in,
                              void* d_out, int out_size, void* d_ws, size_t ws_size,
                              hipStream_t stream) {
  const void* ctx = d_in[0];
  const void* logits = d_in[1];
  const void* s2e = d_in[2];
  const void* intrin = d_in[3];
  const void* ida = d_in[4];
  const void* bda = d_in[5];

  float* wsf = (float*)d_ws;
  int* flags   = (int*)wsf;
  float* mats  = wsf + 16;
  int* counts  = (int*)(wsf + 512);
  int* offsets = (int*)(wsf + 512 + NCELL);
  int* cursors = (int*)(wsf + 512 + 2 * NCELL);
  float* ctx_t = wsf + 512 + 3 * NCELL;
  u16* colids  = (u16*)(ctx_t + NCOL * C_);
  float* wts   = (float*)((float*)colids + MAXT / 2);

  hipMemsetAsync(counts, 0, NCELL * sizeof(int), stream);
  lss_prep<<<1, 256, 0, stream>>>(logits, s2e, intrin, ida, bda, mats, flags);
  lss_transpose<<<(NCOL * C_ + 255) / 256, 256, 0, stream>>>(ctx, flags, ctx_t);
  lss_count<<<NCOL, 64, 0, stream>>>(mats, counts);
  lss_scan<<<1, 1024, 0, stream>>>(counts, offsets, cursors);
  lss_fill<<<NCOL, 64, 0, stream>>>(logits, mats, flags, cursors, colids, wts);
  lss_gather<<<NCELL / GB_CELLS, 1024, 0, stream>>>(ctx_t, counts, offsets, colids, wts, flags, d_out);
}